// Round 5
// baseline (712.672 us; speedup 1.0000x reference)
//
#include <hip/hip_runtime.h>
#include <hip/hip_bf16.h>
#include <stdint.h>

typedef __attribute__((ext_vector_type(4))) float f32x4;
typedef __attribute__((ext_vector_type(8))) short bf16x8;

#define LOG2E 1.44269504088896340736f

__device__ __forceinline__ unsigned short f2bf(float f) {
  union { float f; unsigned u; } c; c.f = f;
  unsigned u = c.u + 0x7FFFu + ((c.u >> 16) & 1u);
  return (unsigned short)(u >> 16);
}

__device__ __forceinline__ void gload_lds16(const void* g, void* l) {
  __builtin_amdgcn_global_load_lds((const __attribute__((address_space(1))) void*)g,
                                   (__attribute__((address_space(3))) void*)l, 16, 0, 0);
}

// ---------------- cast x fp32 -> bf16 ----------------
__global__ __launch_bounds__(256) void cast_x_kernel(const float* __restrict__ x,
                                                     unsigned short* __restrict__ o) {
  int i = blockIdx.x * 256 + threadIdx.x;  // 8 elems per thread
  const float4* xv = (const float4*)x;
  float4 a = xv[2 * i], b = xv[2 * i + 1];
  union { uint4 v; unsigned short s[8]; } u;
  u.s[0] = f2bf(a.x); u.s[1] = f2bf(a.y); u.s[2] = f2bf(a.z); u.s[3] = f2bf(a.w);
  u.s[4] = f2bf(b.x); u.s[5] = f2bf(b.y); u.s[6] = f2bf(b.z); u.s[7] = f2bf(b.w);
  ((uint4*)o)[i] = u.v;
}

// ---------------- fold LoRA into per-head weights, output W_eff^T [n][c] bf16 ----------------
__global__ __launch_bounds__(256) void fold_head_kernel(const float* __restrict__ W,
                                                        const float* __restrict__ A,
                                                        const float* __restrict__ Bm,
                                                        unsigned short* __restrict__ outT,
                                                        float scale) {
  int h = blockIdx.x, cb = blockIdx.y;
  __shared__ unsigned short tile[64 * 65];
  const float* Wh = W + (size_t)h * 65536;
  const float* Ah = A + (size_t)h * 8192;
  const float* Bh = Bm + (size_t)h * 512;
  int t = threadIdx.x;
  for (int i = 0; i < 16; ++i) {
    int idx = i * 256 + t;
    int cl = idx >> 6, d = idx & 63;
    int c = cb * 64 + cl;
    float acc = 0.f;
#pragma unroll
    for (int r = 0; r < 8; ++r) acc += Ah[c * 8 + r] * Bh[r * 64 + d];
    float val = scale * (Wh[c * 64 + d] + 2.0f * acc);
    tile[cl * 65 + d] = f2bf(val);
  }
  __syncthreads();
  for (int i = 0; i < 16; ++i) {
    int idx = i * 256 + t;
    int d = idx >> 6, cl = idx & 63;
    outT[(size_t)(h * 64 + d) * 1024 + cb * 64 + cl] = tile[cl * 65 + d];
  }
}

// ---------------- fold proj LoRA ----------------
__global__ __launch_bounds__(256) void fold_proj_kernel(const float* __restrict__ W,
                                                        const float* __restrict__ A,
                                                        const float* __restrict__ Bm,
                                                        unsigned short* __restrict__ outT) {
  int nb = blockIdx.x, cb = blockIdx.y;
  __shared__ unsigned short tile[64 * 65];
  int t = threadIdx.x;
  for (int i = 0; i < 16; ++i) {
    int idx = i * 256 + t;
    int cl = idx >> 6, d = idx & 63;
    int c = cb * 64 + cl, n = nb * 64 + d;
    float acc = 0.f;
#pragma unroll
    for (int r = 0; r < 8; ++r) acc += A[c * 8 + r] * Bm[r * 1024 + n];
    float val = W[(size_t)c * 1024 + n] + 2.0f * acc;
    tile[cl * 65 + d] = f2bf(val);
  }
  __syncthreads();
  for (int i = 0; i < 16; ++i) {
    int idx = i * 256 + t;
    int d = idx >> 6, cl = idx & 63;
    outT[(size_t)(nb * 64 + d) * 1024 + cb * 64 + cl] = tile[cl * 65 + d];
  }
}

// ---------------- GEMM: C[M][N] = A[M][K] * B^T (B stored [N][K]), bf16 in, fp32 acc ----------------
template <int MODE>
__global__ __launch_bounds__(256) void gemm_kernel(const unsigned short* __restrict__ A,
                                                   const unsigned short* __restrict__ B,
                                                   void* __restrict__ Cout,
                                                   const float* __restrict__ bias,
                                                   int M, int N, int K) {
  __shared__ unsigned short lds[8192];
  const int t = threadIdx.x;
  const int m0 = blockIdx.y * 128, n0 = blockIdx.x * 128;
  const int wid = t >> 6, lane = t & 63;
  const int wm = (wid >> 1) * 64, wn = (wid & 1) * 64;
  const int lr = lane & 15, lg = lane >> 4;
  f32x4 acc[4][4];
#pragma unroll
  for (int i = 0; i < 4; ++i)
#pragma unroll
    for (int j = 0; j < 4; ++j) acc[i][j] = (f32x4){0.f, 0.f, 0.f, 0.f};

  for (int k0 = 0; k0 < K; k0 += 32) {
#pragma unroll
    for (int ch = 0; ch < 2; ++ch) {
      int idx = ch * 256 + t;
      int row = idx >> 2, cb = (idx & 3) * 8;
      gload_lds16(A + (size_t)(m0 + row) * K + k0 + cb, &lds[idx * 8]);
    }
#pragma unroll
    for (int ch = 0; ch < 2; ++ch) {
      int idx = ch * 256 + t;
      int row = idx >> 2, cb = (idx & 3) * 8;
      gload_lds16(B + (size_t)(n0 + row) * K + k0 + cb, &lds[4096 + idx * 8]);
    }
    __syncthreads();
    bf16x8 af[4], bfr[4];
#pragma unroll
    for (int i = 0; i < 4; ++i) {
      af[i] = *(const bf16x8*)&lds[(wm + i * 16 + lr) * 32 + lg * 8];
      bfr[i] = *(const bf16x8*)&lds[4096 + (wn + i * 16 + lr) * 32 + lg * 8];
    }
#pragma unroll
    for (int i = 0; i < 4; ++i)
#pragma unroll
      for (int j = 0; j < 4; ++j)
        acc[i][j] = __builtin_amdgcn_mfma_f32_16x16x32_bf16(af[i], bfr[j], acc[i][j], 0, 0, 0);
    __syncthreads();
  }

#pragma unroll
  for (int i = 0; i < 4; ++i) {
#pragma unroll
    for (int r = 0; r < 4; ++r) {
      int row = m0 + wm + i * 16 + lg * 4 + r;
#pragma unroll
      for (int j = 0; j < 4; ++j) {
        int col = n0 + wn + j * 16 + lr;
        float v = acc[i][j][r];
        if (MODE == 0)
          ((unsigned short*)Cout)[(size_t)row * N + col] = f2bf(v);
        else
          ((float*)Cout)[(size_t)row * N + col] = v + bias[col];
      }
    }
  }
}

// ---------------- causal flash attention v3 ----------------
// qkv: [B*T][3072] bf16, q pre-scaled by 0.125*log2(e)  ->  P = exp2(S)
// out: [B*T][1024] bf16 (head-concat)
// 2048 blocks: one 64-row q-tile each. XCD-local bh mapping + longest-first order.
// Single-buffered KV (24KB LDS -> 6 blocks/CU = 24 waves), T14 reg-prefetch.
// S^T = mfma(K,Q): lane owns 4 consecutive keys of one q-row -> b64 P-writes.
__global__ __launch_bounds__(256, 6) void attn_kernel(const unsigned short* __restrict__ qkv,
                                                      unsigned short* __restrict__ out) {
  __shared__ __align__(16) char kl[8192];  // K tile [64 key][64 d], swz (key&7)<<4
  __shared__ __align__(16) char vt[8192];  // V^T tile [64 d][64 key], swz ((d&7)^((d>>3)&7))<<4
  __shared__ __align__(16) char pl[8192];  // per-wave P [16 q][64 key], swz ((q&1)<<4)|((q&12)<<3)
  const int t = threadIdx.x;
  const int wid = t >> 6, lane = t & 63;
  const int lr = lane & 15, lg = lane >> 4;
  // XCD-local mapping: all 32 q-tiles of a bh on one XCD; longest q-tiles dispatched first
  const int i = blockIdx.x;
  const int xcd = i & 7, s = i >> 3;
  const int bh = xcd + 8 * (s >> 5);
  const int qtile = 31 - (s & 31);
  const int b = bh >> 4, h = bh & 15;
  const size_t baseRow = (size_t)b * 2048;
  const int nkt = qtile + 1;
  const int q0w = qtile * 64 + wid * 16;
  char* pb = pl + wid * 2048;
  const int s_kr = t >> 3;  // 0..31 staging row (second chunk adds 32)
  const int s_cb = t & 7;   // 16B chunk
  const int swP = ((lr & 1) << 4) | ((lr & 12) << 3);

  // Q fragment (B-operand: n = q = lane&15)
  const unsigned short* qp = qkv + (baseRow + q0w + lr) * 3072 + h * 64 + lg * 8;
  bf16x8 qf0 = *(const bf16x8*)qp;
  bf16x8 qf1 = *(const bf16x8*)(qp + 32);

  f32x4 acc_o[4];
#pragma unroll
  for (int d = 0; d < 4; ++d) acc_o[d] = (f32x4){0.f, 0.f, 0.f, 0.f};
  float l_acc = 0.f;  // per-lane: running denom for q-row lr

  auto loadKV = [&](int kt, uint4* kreg, uint4* vreg) {
    const unsigned short* base = qkv + (baseRow + kt * 64) * 3072 + h * 64 + s_cb * 8;
    kreg[0] = *(const uint4*)(base + 1024 + (size_t)s_kr * 3072);
    kreg[1] = *(const uint4*)(base + 1024 + (size_t)(s_kr + 32) * 3072);
    vreg[0] = *(const uint4*)(base + 2048 + (size_t)s_kr * 3072);
    vreg[1] = *(const uint4*)(base + 2048 + (size_t)(s_kr + 32) * 3072);
  };
  auto storeKV = [&](uint4* kreg, uint4* vreg) {
#pragma unroll
    for (int ch = 0; ch < 2; ++ch) {
      int kr = ch * 32 + s_kr;
      *(uint4*)(kl + kr * 128 + ((s_cb * 16) ^ ((kr & 7) << 4))) = kreg[ch];
    }
#pragma unroll
    for (int ch = 0; ch < 2; ++ch) {
      int kr = ch * 32 + s_kr;
      union { uint4 v; unsigned w[4]; unsigned short s[8]; } u, p;
      u.v = vreg[ch];
#pragma unroll
      for (int c2 = 0; c2 < 4; ++c2) p.w[c2] = (unsigned)__shfl_xor((int)u.w[c2], 8);
      const int krE2 = (kr & ~1) * 2;
      const bool ev = (kr & 1) == 0;
#pragma unroll
      for (int jj = 0; jj < 4; ++jj) {
        int j = ev ? jj : jj + 4;
        unsigned lo = ev ? u.s[j] : p.s[j];
        unsigned hi = ev ? p.s[j] : u.s[j];
        int d = s_cb * 8 + j;
        int sw = (((d & 7) ^ ((d >> 3) & 7)) << 4);
        *(unsigned*)(vt + d * 128 + (krE2 ^ sw)) = lo | (hi << 16);
      }
    }
  };

  {  // prologue: stage tile 0
    uint4 kreg[2], vreg[2];
    loadKV(0, kreg, vreg);
    storeKV(kreg, vreg);
  }
  __syncthreads();

#pragma unroll 1
  for (int kt = 0; kt < nkt; ++kt) {
    uint4 kreg2[2], vreg2[2];
    const bool pf = (kt + 1 < nkt);
    if (pf) loadKV(kt + 1, kreg2, vreg2);  // issue early (T14)

    // ---- S^T = K Q^T : z[nt] holds S[key=nt*16+lg*4+r][q=lr] ----
    f32x4 z[4];
#pragma unroll
    for (int nt = 0; nt < 4; ++nt) {
      int key = nt * 16 + lr;
      const char* kb = kl + key * 128;
      int sw = (key & 7) << 4;
      bf16x8 kf0 = *(const bf16x8*)(kb + ((lg * 16) ^ sw));
      bf16x8 kf1 = *(const bf16x8*)(kb + ((64 + lg * 16) ^ sw));
      f32x4 zz = (f32x4){0.f, 0.f, 0.f, 0.f};
      zz = __builtin_amdgcn_mfma_f32_16x16x32_bf16(kf0, qf0, zz, 0, 0, 0);
      zz = __builtin_amdgcn_mfma_f32_16x16x32_bf16(kf1, qf1, zz, 0, 0, 0);
      z[nt] = zz;
    }
    // ---- P = exp2(S^T) with fused causal mask (diagonal tile only); b64 P-writes ----
    const bool diag = (kt == qtile);
    const int qg = q0w + lr;
#pragma unroll
    for (int nt = 0; nt < 4; ++nt) {
      union { uint2 v; unsigned short us[4]; } pk;
#pragma unroll
      for (int r = 0; r < 4; ++r) {
        float pv = exp2f(z[nt][r]);
        if (diag) {
          int keyg = kt * 64 + nt * 16 + lg * 4 + r;
          pv = (keyg > qg) ? 0.f : pv;
        }
        l_acc += pv;
        pk.us[r] = f2bf(pv);
      }
      *(uint2*)(pb + lr * 128 + (((nt * 16 + lg * 4) * 2) ^ swP)) = pk.v;
    }
    // ---- O += P V  (P is wave-private: no barrier needed) ----
#pragma unroll
    for (int kk = 0; kk < 2; ++kk) {
      bf16x8 pfr = *(const bf16x8*)(pb + lr * 128 + ((kk * 64 + lg * 16) ^ swP));
#pragma unroll
      for (int dt = 0; dt < 4; ++dt) {
        int d = dt * 16 + lr;
        int swv = (((d & 7) ^ ((d >> 3) & 7)) << 4);
        bf16x8 vf = *(const bf16x8*)(vt + d * 128 + ((kk * 64 + lg * 16) ^ swv));
        acc_o[dt] = __builtin_amdgcn_mfma_f32_16x16x32_bf16(pfr, vf, acc_o[dt], 0, 0, 0);
      }
    }

    __syncthreads();  // all waves done reading kl/vt
    if (pf) {
      storeKV(kreg2, vreg2);  // overwrite single buffer (vmcnt wait was hidden under compute)
      __syncthreads();
    }
  }

  // ---- epilogue: reduce l across lg groups, broadcast, normalize, store ----
  float lsum = l_acc;
  lsum += __shfl_xor(lsum, 16);
  lsum += __shfl_xor(lsum, 32);  // every lane now has l[q = lr]
#pragma unroll
  for (int r = 0; r < 4; ++r) {
    float inv = 1.0f / __shfl(lsum, lg * 4 + r);
    unsigned short* op = out + (baseRow + q0w + lg * 4 + r) * 1024 + h * 64;
#pragma unroll
    for (int dt = 0; dt < 4; ++dt) op[dt * 16 + lr] = f2bf(acc_o[dt][r] * inv);
  }
}

extern "C" void kernel_launch(void* const* d_in, const int* in_sizes, int n_in,
                              void* d_out, int out_size, void* d_ws, size_t ws_size,
                              hipStream_t stream) {
  const float* x = (const float*)d_in[0];
  const float* Wq = (const float*)d_in[1];
  const float* Wk = (const float*)d_in[2];
  const float* Wv = (const float*)d_in[3];
  const float* Aq = (const float*)d_in[4];
  const float* Bq = (const float*)d_in[5];
  const float* Ak = (const float*)d_in[6];
  const float* Bk = (const float*)d_in[7];
  const float* Av = (const float*)d_in[8];
  const float* Bv = (const float*)d_in[9];
  const float* Wp = (const float*)d_in[10];
  const float* bp = (const float*)d_in[11];
  const float* Ap = (const float*)d_in[12];
  const float* Bp = (const float*)d_in[13];

  unsigned short* xb = (unsigned short*)d_ws;
  unsigned short* weff = xb + 8388608;
  unsigned short* wpeff = weff + 3145728;
  unsigned short* qkvb = wpeff + 1048576;
  unsigned short* attb = xb;  // alias: x dead after QKV GEMM

  cast_x_kernel<<<4096, 256, 0, stream>>>(x, xb);
  dim3 fg(16, 16);
  // q scale = softmax 1/8, with log2(e) folded so attention uses exp2 directly
  fold_head_kernel<<<fg, 256, 0, stream>>>(Wq, Aq, Bq, weff, 0.125f * LOG2E);
  fold_head_kernel<<<fg, 256, 0, stream>>>(Wk, Ak, Bk, weff + 1048576, 1.0f);
  fold_head_kernel<<<fg, 256, 0, stream>>>(Wv, Av, Bv, weff + 2097152, 1.0f);
  fold_proj_kernel<<<fg, 256, 0, stream>>>(Wp, Ap, Bp, wpeff);

  gemm_kernel<0><<<dim3(24, 64), 256, 0, stream>>>(xb, weff, (void*)qkvb, nullptr, 8192, 3072, 1024);
  attn_kernel<<<2048, 256, 0, stream>>>(qkvb, attb);
  gemm_kernel<1><<<dim3(8, 64), 256, 0, stream>>>(attb, wpeff, d_out, bp, 8192, 1024, 1024);
}

// Round 7
// 336.382 us; speedup vs baseline: 2.1186x; 2.1186x over previous
//
#include <hip/hip_runtime.h>
#include <hip/hip_bf16.h>
#include <stdint.h>

typedef __attribute__((ext_vector_type(4))) float f32x4;
typedef __attribute__((ext_vector_type(8))) short bf16x8;

#define LOG2E 1.44269504088896340736f

__device__ __forceinline__ unsigned short f2bf(float f) {
  union { float f; unsigned u; } c; c.f = f;
  unsigned u = c.u + 0x7FFFu + ((c.u >> 16) & 1u);
  return (unsigned short)(u >> 16);
}

__device__ __forceinline__ void gload_lds16(const void* g, void* l) {
  __builtin_amdgcn_global_load_lds((const __attribute__((address_space(1))) void*)g,
                                   (__attribute__((address_space(3))) void*)l, 16, 0, 0);
}

// ---------------- cast x fp32 -> bf16 ----------------
__global__ __launch_bounds__(256) void cast_x_kernel(const float* __restrict__ x,
                                                     unsigned short* __restrict__ o) {
  int i = blockIdx.x * 256 + threadIdx.x;  // 8 elems per thread
  const float4* xv = (const float4*)x;
  float4 a = xv[2 * i], b = xv[2 * i + 1];
  union { uint4 v; unsigned short s[8]; } u;
  u.s[0] = f2bf(a.x); u.s[1] = f2bf(a.y); u.s[2] = f2bf(a.z); u.s[3] = f2bf(a.w);
  u.s[4] = f2bf(b.x); u.s[5] = f2bf(b.y); u.s[6] = f2bf(b.z); u.s[7] = f2bf(b.w);
  ((uint4*)o)[i] = u.v;
}

// ---------------- fold LoRA into per-head weights, output W_eff^T [n][c] bf16 ----------------
__global__ __launch_bounds__(256) void fold_head_kernel(const float* __restrict__ W,
                                                        const float* __restrict__ A,
                                                        const float* __restrict__ Bm,
                                                        unsigned short* __restrict__ outT,
                                                        float scale) {
  int h = blockIdx.x, cb = blockIdx.y;
  __shared__ unsigned short tile[64 * 65];
  const float* Wh = W + (size_t)h * 65536;
  const float* Ah = A + (size_t)h * 8192;
  const float* Bh = Bm + (size_t)h * 512;
  int t = threadIdx.x;
  for (int i = 0; i < 16; ++i) {
    int idx = i * 256 + t;
    int cl = idx >> 6, d = idx & 63;
    int c = cb * 64 + cl;
    float acc = 0.f;
#pragma unroll
    for (int r = 0; r < 8; ++r) acc += Ah[c * 8 + r] * Bh[r * 64 + d];
    float val = scale * (Wh[c * 64 + d] + 2.0f * acc);
    tile[cl * 65 + d] = f2bf(val);
  }
  __syncthreads();
  for (int i = 0; i < 16; ++i) {
    int idx = i * 256 + t;
    int d = idx >> 6, cl = idx & 63;
    outT[(size_t)(h * 64 + d) * 1024 + cb * 64 + cl] = tile[cl * 65 + d];
  }
}

// ---------------- fold proj LoRA ----------------
__global__ __launch_bounds__(256) void fold_proj_kernel(const float* __restrict__ W,
                                                        const float* __restrict__ A,
                                                        const float* __restrict__ Bm,
                                                        unsigned short* __restrict__ outT) {
  int nb = blockIdx.x, cb = blockIdx.y;
  __shared__ unsigned short tile[64 * 65];
  int t = threadIdx.x;
  for (int i = 0; i < 16; ++i) {
    int idx = i * 256 + t;
    int cl = idx >> 6, d = idx & 63;
    int c = cb * 64 + cl, n = nb * 64 + d;
    float acc = 0.f;
#pragma unroll
    for (int r = 0; r < 8; ++r) acc += A[c * 8 + r] * Bm[r * 1024 + n];
    float val = W[(size_t)c * 1024 + n] + 2.0f * acc;
    tile[cl * 65 + d] = f2bf(val);
  }
  __syncthreads();
  for (int i = 0; i < 16; ++i) {
    int idx = i * 256 + t;
    int d = idx >> 6, cl = idx & 63;
    outT[(size_t)(nb * 64 + d) * 1024 + cb * 64 + cl] = tile[cl * 65 + d];
  }
}

// ---------------- GEMM: C[M][N] = A[M][K] * B^T (B stored [N][K]), bf16 in, fp32 acc ----------------
template <int MODE>
__global__ __launch_bounds__(256) void gemm_kernel(const unsigned short* __restrict__ A,
                                                   const unsigned short* __restrict__ B,
                                                   void* __restrict__ Cout,
                                                   const float* __restrict__ bias,
                                                   int M, int N, int K) {
  __shared__ unsigned short lds[8192];
  const int t = threadIdx.x;
  const int m0 = blockIdx.y * 128, n0 = blockIdx.x * 128;
  const int wid = t >> 6, lane = t & 63;
  const int wm = (wid >> 1) * 64, wn = (wid & 1) * 64;
  const int lr = lane & 15, lg = lane >> 4;
  f32x4 acc[4][4];
#pragma unroll
  for (int i = 0; i < 4; ++i)
#pragma unroll
    for (int j = 0; j < 4; ++j) acc[i][j] = (f32x4){0.f, 0.f, 0.f, 0.f};

  for (int k0 = 0; k0 < K; k0 += 32) {
#pragma unroll
    for (int ch = 0; ch < 2; ++ch) {
      int idx = ch * 256 + t;
      int row = idx >> 2, cb = (idx & 3) * 8;
      gload_lds16(A + (size_t)(m0 + row) * K + k0 + cb, &lds[idx * 8]);
    }
#pragma unroll
    for (int ch = 0; ch < 2; ++ch) {
      int idx = ch * 256 + t;
      int row = idx >> 2, cb = (idx & 3) * 8;
      gload_lds16(B + (size_t)(n0 + row) * K + k0 + cb, &lds[4096 + idx * 8]);
    }
    __syncthreads();
    bf16x8 af[4], bfr[4];
#pragma unroll
    for (int i = 0; i < 4; ++i) {
      af[i] = *(const bf16x8*)&lds[(wm + i * 16 + lr) * 32 + lg * 8];
      bfr[i] = *(const bf16x8*)&lds[4096 + (wn + i * 16 + lr) * 32 + lg * 8];
    }
#pragma unroll
    for (int i = 0; i < 4; ++i)
#pragma unroll
      for (int j = 0; j < 4; ++j)
        acc[i][j] = __builtin_amdgcn_mfma_f32_16x16x32_bf16(af[i], bfr[j], acc[i][j], 0, 0, 0);
    __syncthreads();
  }

#pragma unroll
  for (int i = 0; i < 4; ++i) {
#pragma unroll
    for (int r = 0; r < 4; ++r) {
      int row = m0 + wm + i * 16 + lg * 4 + r;
#pragma unroll
      for (int j = 0; j < 4; ++j) {
        int col = n0 + wn + j * 16 + lr;
        float v = acc[i][j][r];
        if (MODE == 0)
          ((unsigned short*)Cout)[(size_t)row * N + col] = f2bf(v);
        else
          ((float*)Cout)[(size_t)row * N + col] = v + bias[col];
      }
    }
  }
}

// ---------------- V transpose: qkv V part [b,t,h,d] -> vtb [(b*16+h)*64+d][t] ----------------
__global__ __launch_bounds__(256) void vtrans_kernel(const unsigned short* __restrict__ qkv,
                                                     unsigned short* __restrict__ vtb) {
  __shared__ unsigned short tile[64][66];  // [t][d], pad 2 (stride 132B: 4B-aligned, low conflict)
  const int tt = blockIdx.x, bh = blockIdx.y;
  const int b = bh >> 4, h = bh & 15;
  const size_t srcBase = ((size_t)b * 2048 + tt * 64) * 3072 + 2048 + h * 64;
  const int t = threadIdx.x;
#pragma unroll
  for (int ch = 0; ch < 2; ++ch) {
    int idx = ch * 256 + t;           // 0..511
    int tl = idx >> 3, c = idx & 7;   // local t row, 16B chunk
    *(uint4*)&tile[tl][c * 8] = *(const uint4*)(qkv + srcBase + (size_t)tl * 3072 + c * 8);
  }
  __syncthreads();
#pragma unroll
  for (int ch = 0; ch < 2; ++ch) {
    int idx = ch * 256 + t;
    int d = idx >> 3, tc = idx & 7;   // out row d, 8-key chunk
    union { uint4 v; unsigned short s[8]; } u;
#pragma unroll
    for (int j = 0; j < 8; ++j) u.s[j] = tile[tc * 8 + j][d];
    *(uint4*)(vtb + ((size_t)bh * 64 + d) * 2048 + tt * 64 + tc * 8) = u.v;
  }
}

// ---------------- causal flash attention v4 ----------------
// qkv: [B*T][3072] bf16 (q pre-scaled by 0.125*log2e); vtb: V^T [bh*64+d][t]
// out: [B*T][1024] bf16. 2048 blocks, one 64-row q-tile each; XCD-local bh mapping,
// longest-first. Double-buffered K/V^T via global_load_lds (async DMA, ZERO staging
// VGPRs -> no spills). Source-chunk pre-swizzle reproduces the verified r5 LDS layouts.
__global__ __launch_bounds__(256) void attn_kernel(const unsigned short* __restrict__ qkv,
                                                   const unsigned short* __restrict__ vtb,
                                                   unsigned short* __restrict__ out) {
  __shared__ __align__(16) char kl[2][8192];  // K [key][d], LDS[kr][c'] = K[kr][c'^(kr&7)]
  __shared__ __align__(16) char vt[2][8192];  // V^T [d][key], LDS[d][c'] = VT[d][c'^swf(d)]
  __shared__ __align__(16) char pl[8192];     // per-wave P [16 q][64 key]
  const int t = threadIdx.x;
  const int wid = t >> 6, lane = t & 63;
  const int lr = lane & 15, lg = lane >> 4;
  // XCD-local mapping (2048 % 8 == 0: bijective); longest q-tiles first
  const int i = blockIdx.x;
  const int xcd = i & 7, s = i >> 3;
  const int bh = xcd + 8 * (s >> 5);
  const int qtile = 31 - (s & 31);
  const int b = bh >> 4, h = bh & 15;
  const size_t baseRow = (size_t)b * 2048;
  const int nkt = qtile + 1;
  const int q0w = qtile * 64 + wid * 16;
  char* pb = pl + wid * 2048;
  const int swP = ((lr & 1) << 4) | ((lr & 12) << 3);
  const int srow = lane >> 3;  // staging row within wave-instr
  const int sc = lane & 7;     // staging chunk

  const unsigned short* qp = qkv + (baseRow + q0w + lr) * 3072 + h * 64 + lg * 8;
  bf16x8 qf0 = *(const bf16x8*)qp;
  bf16x8 qf1 = *(const bf16x8*)(qp + 32);

  f32x4 acc_o[4];
#pragma unroll
  for (int d = 0; d < 4; ++d) acc_o[d] = (f32x4){0.f, 0.f, 0.f, 0.f};
  float l_acc = 0.f;

  const unsigned short* vrow = vtb + (size_t)bh * 131072;  // 64 rows * 2048

  auto stage = [&](int kt, int buf) {
#pragma unroll
    for (int ch = 0; ch < 2; ++ch) {
      int kr = ch * 32 + wid * 8 + srow;
      int gc = sc ^ (kr & 7);
      gload_lds16(qkv + (baseRow + kt * 64 + kr) * 3072 + 1024 + h * 64 + gc * 8,
                  &kl[buf][(ch * 256 + t) * 16]);
    }
#pragma unroll
    for (int ch = 0; ch < 2; ++ch) {
      int d = ch * 32 + wid * 8 + srow;
      int gc = sc ^ (((d & 7) ^ (d >> 3)) & 7);
      gload_lds16(vrow + (size_t)d * 2048 + kt * 64 + gc * 8,
                  &vt[buf][(ch * 256 + t) * 16]);
    }
  };

  stage(0, 0);
  __syncthreads();  // drains DMA (compiler emits vmcnt(0) before barrier)

#pragma unroll 1
  for (int kt = 0; kt < nkt; ++kt) {
    const int cur = kt & 1;
    if (kt + 1 < nkt) stage(kt + 1, cur ^ 1);  // async DMA overlaps compute below

    // ---- S^T = K Q^T : z[nt] holds S[key=nt*16+lg*4+r][q=lr] ----
    const char* klc = kl[cur];
    f32x4 z[4];
#pragma unroll
    for (int nt = 0; nt < 4; ++nt) {
      int key = nt * 16 + lr;
      const char* kb = klc + key * 128;
      int sw = (key & 7) << 4;
      bf16x8 kf0 = *(const bf16x8*)(kb + ((lg * 16) ^ sw));
      bf16x8 kf1 = *(const bf16x8*)(kb + ((64 + lg * 16) ^ sw));
      f32x4 zz = (f32x4){0.f, 0.f, 0.f, 0.f};
      zz = __builtin_amdgcn_mfma_f32_16x16x32_bf16(kf0, qf0, zz, 0, 0, 0);
      zz = __builtin_amdgcn_mfma_f32_16x16x32_bf16(kf1, qf1, zz, 0, 0, 0);
      z[nt] = zz;
    }
    // ---- P = exp2(S^T), fused causal mask on diagonal; b64 P-writes ----
    const bool diag = (kt == qtile);
    const int qg = q0w + lr;
#pragma unroll
    for (int nt = 0; nt < 4; ++nt) {
      union { uint2 v; unsigned short us[4]; } pk;
#pragma unroll
      for (int r = 0; r < 4; ++r) {
        float pv = exp2f(z[nt][r]);
        if (diag) {
          int keyg = kt * 64 + nt * 16 + lg * 4 + r;
          pv = (keyg > qg) ? 0.f : pv;
        }
        l_acc += pv;
        pk.us[r] = f2bf(pv);
      }
      *(uint2*)(pb + lr * 128 + (((nt * 16 + lg * 4) * 2) ^ swP)) = pk.v;
    }
    // ---- O += P V  (P wave-private: no barrier needed) ----
#pragma unroll
    for (int kk = 0; kk < 2; ++kk) {
      bf16x8 pfr = *(const bf16x8*)(pb + lr * 128 + ((kk * 64 + lg * 16) ^ swP));
#pragma unroll
      for (int dt = 0; dt < 4; ++dt) {
        int d = dt * 16 + lr;
        int swv = (((d & 7) ^ ((d >> 3) & 7)) << 4);
        bf16x8 vf = *(const bf16x8*)(vt[cur] + d * 128 + ((kk * 64 + lg * 16) ^ swv));
        acc_o[dt] = __builtin_amdgcn_mfma_f32_16x16x32_bf16(pfr, vf, acc_o[dt], 0, 0, 0);
      }
    }

    __syncthreads();  // drains this iter's DMA (next buffer ready), fences buffer reuse
  }

  // ---- epilogue: reduce l across lg groups, broadcast, normalize, store ----
  float lsum = l_acc;
  lsum += __shfl_xor(lsum, 16);
  lsum += __shfl_xor(lsum, 32);  // every lane now has l[q = lr]
#pragma unroll
  for (int r = 0; r < 4; ++r) {
    float inv = 1.0f / __shfl(lsum, lg * 4 + r);
    unsigned short* op = out + (baseRow + q0w + lg * 4 + r) * 1024 + h * 64;
#pragma unroll
    for (int dt = 0; dt < 4; ++dt) op[dt * 16 + lr] = f2bf(acc_o[dt][r] * inv);
  }
}

extern "C" void kernel_launch(void* const* d_in, const int* in_sizes, int n_in,
                              void* d_out, int out_size, void* d_ws, size_t ws_size,
                              hipStream_t stream) {
  const float* x = (const float*)d_in[0];
  const float* Wq = (const float*)d_in[1];
  const float* Wk = (const float*)d_in[2];
  const float* Wv = (const float*)d_in[3];
  const float* Aq = (const float*)d_in[4];
  const float* Bq = (const float*)d_in[5];
  const float* Ak = (const float*)d_in[6];
  const float* Bk = (const float*)d_in[7];
  const float* Av = (const float*)d_in[8];
  const float* Bv = (const float*)d_in[9];
  const float* Wp = (const float*)d_in[10];
  const float* bp = (const float*)d_in[11];
  const float* Ap = (const float*)d_in[12];
  const float* Bp = (const float*)d_in[13];

  // workspace carve (bf16 elems): xb 16.8MB (reused as attn out) | weff 6.3 | wpeff 2.1
  //                               | qkvb 50.3 | vtb 16.8  => peak ~92.3 MB
  unsigned short* xb = (unsigned short*)d_ws;
  unsigned short* weff = xb + 8388608;
  unsigned short* wpeff = weff + 3145728;
  unsigned short* qkvb = wpeff + 1048576;
  unsigned short* vtb = qkvb + 25165824;
  unsigned short* attb = xb;  // alias: x dead after QKV GEMM

  cast_x_kernel<<<4096, 256, 0, stream>>>(x, xb);
  dim3 fg(16, 16);
  // q scale = softmax 1/8, with log2(e) folded so attention uses exp2 directly
  fold_head_kernel<<<fg, 256, 0, stream>>>(Wq, Aq, Bq, weff, 0.125f * LOG2E);
  fold_head_kernel<<<fg, 256, 0, stream>>>(Wk, Ak, Bk, weff + 1048576, 1.0f);
  fold_head_kernel<<<fg, 256, 0, stream>>>(Wv, Av, Bv, weff + 2097152, 1.0f);
  fold_proj_kernel<<<fg, 256, 0, stream>>>(Wp, Ap, Bp, wpeff);

  gemm_kernel<0><<<dim3(24, 64), 256, 0, stream>>>(xb, weff, (void*)qkvb, nullptr, 8192, 3072, 1024);
  vtrans_kernel<<<dim3(32, 64), 256, 0, stream>>>(qkvb, vtb);
  attn_kernel<<<2048, 256, 0, stream>>>(qkvb, vtb, attb);
  gemm_kernel<1><<<dim3(8, 64), 256, 0, stream>>>(attb, wpeff, d_out, bp, 8192, 1024, 1024);
}

// Round 8
// 329.361 us; speedup vs baseline: 2.1638x; 1.0213x over previous
//
#include <hip/hip_runtime.h>
#include <hip/hip_bf16.h>
#include <stdint.h>

typedef __attribute__((ext_vector_type(4))) float f32x4;
typedef __attribute__((ext_vector_type(8))) short bf16x8;

#define LOG2E 1.44269504088896340736f

__device__ __forceinline__ unsigned short f2bf(float f) {
  union { float f; unsigned u; } c; c.f = f;
  unsigned u = c.u + 0x7FFFu + ((c.u >> 16) & 1u);
  return (unsigned short)(u >> 16);
}

__device__ __forceinline__ void gload_lds16(const void* g, void* l) {
  __builtin_amdgcn_global_load_lds((const __attribute__((address_space(1))) void*)g,
                                   (__attribute__((address_space(3))) void*)l, 16, 0, 0);
}

// ---------------- cast x fp32 -> bf16 ----------------
__global__ __launch_bounds__(256) void cast_x_kernel(const float* __restrict__ x,
                                                     unsigned short* __restrict__ o) {
  int i = blockIdx.x * 256 + threadIdx.x;
  const float4* xv = (const float4*)x;
  float4 a = xv[2 * i], b = xv[2 * i + 1];
  union { uint4 v; unsigned short s[8]; } u;
  u.s[0] = f2bf(a.x); u.s[1] = f2bf(a.y); u.s[2] = f2bf(a.z); u.s[3] = f2bf(a.w);
  u.s[4] = f2bf(b.x); u.s[5] = f2bf(b.y); u.s[6] = f2bf(b.z); u.s[7] = f2bf(b.w);
  ((uint4*)o)[i] = u.v;
}

// ---------------- fold LoRA into per-head weights -> W_eff^T [n][c] bf16 ----------------
// W[h][c][d], A[h][c][r], Bm[h][r][d]; out row n = h*64+d. B staged in LDS, A as float4x2.
__global__ __launch_bounds__(256) void fold_head_kernel(const float* __restrict__ W,
                                                        const float* __restrict__ A,
                                                        const float* __restrict__ Bm,
                                                        unsigned short* __restrict__ outT,
                                                        float scale) {
  int h = blockIdx.x, cb = blockIdx.y;
  __shared__ float Bs[8][64];
  __shared__ unsigned short tile[64][65];
  int t = threadIdx.x;
  if (t < 128) ((float4*)&Bs[0][0])[t] = ((const float4*)(Bm + (size_t)h * 512))[t];
  __syncthreads();
  int cl = t >> 2;
  int c = cb * 64 + cl;
  int dbase = (t & 3) * 16;
  float4 a0 = *(const float4*)(A + (size_t)h * 8192 + c * 8);
  float4 a1 = *(const float4*)(A + (size_t)h * 8192 + c * 8 + 4);
  const float* Wc = W + (size_t)h * 65536 + (size_t)c * 64;
#pragma unroll
  for (int j = 0; j < 16; ++j) {
    int d = dbase + j;
    float acc = a0.x * Bs[0][d] + a0.y * Bs[1][d] + a0.z * Bs[2][d] + a0.w * Bs[3][d] +
                a1.x * Bs[4][d] + a1.y * Bs[5][d] + a1.z * Bs[6][d] + a1.w * Bs[7][d];
    tile[cl][d] = f2bf(scale * (Wc[d] + 2.0f * acc));
  }
  __syncthreads();
#pragma unroll
  for (int i = 0; i < 16; ++i) {
    int idx = i * 256 + t;
    int d = idx >> 6, c2 = idx & 63;
    outT[(size_t)(h * 64 + d) * 1024 + cb * 64 + c2] = tile[c2][d];
  }
}

// ---------------- fold proj LoRA -> Wp_eff^T [n][c] bf16 ----------------
__global__ __launch_bounds__(256) void fold_proj_kernel(const float* __restrict__ W,
                                                        const float* __restrict__ A,
                                                        const float* __restrict__ Bm,
                                                        unsigned short* __restrict__ outT) {
  int nb = blockIdx.x, cb = blockIdx.y;
  __shared__ float Bs[8][64];
  __shared__ unsigned short tile[64][65];
  int t = threadIdx.x;
  if (t < 128) {
    int r = t >> 4, dc = t & 15;
    *(float4*)&Bs[r][dc * 4] = *(const float4*)(Bm + (size_t)r * 1024 + nb * 64 + dc * 4);
  }
  __syncthreads();
  int cl = t >> 2;
  int c = cb * 64 + cl;
  int dbase = (t & 3) * 16;
  float4 a0 = *(const float4*)(A + (size_t)c * 8);
  float4 a1 = *(const float4*)(A + (size_t)c * 8 + 4);
  const float* Wc = W + (size_t)c * 1024 + nb * 64;
#pragma unroll
  for (int j = 0; j < 16; ++j) {
    int d = dbase + j;
    float acc = a0.x * Bs[0][d] + a0.y * Bs[1][d] + a0.z * Bs[2][d] + a0.w * Bs[3][d] +
                a1.x * Bs[4][d] + a1.y * Bs[5][d] + a1.z * Bs[6][d] + a1.w * Bs[7][d];
    tile[cl][d] = f2bf(Wc[d] + 2.0f * acc);
  }
  __syncthreads();
#pragma unroll
  for (int i = 0; i < 16; ++i) {
    int idx = i * 256 + t;
    int d = idx >> 6, c2 = idx & 63;
    outT[(size_t)(nb * 64 + d) * 1024 + cb * 64 + c2] = tile[c2][d];
  }
}

// ---------------- 256x256 GEMM: C[M][N] = A[M][K]*B[N][K]^T, bf16 in, fp32 acc ----------------
// 512 thr = 8 waves (2M x 4N); BK=64 double-buffered (128KB LDS); global_load_lds staging
// with pre-swizzled source (chunk c' = c ^ (row&7)); 4 quadrant-phases/K-tile, setprio MFMA.
// MODE 0: bf16 out; MODE 1: fp32 out + bias.
template <int MODE>
__global__ __launch_bounds__(512) void gemm256_kernel(const unsigned short* __restrict__ A,
                                                      const unsigned short* __restrict__ B,
                                                      void* __restrict__ Cout,
                                                      const float* __restrict__ bias,
                                                      int M, int N, int K) {
  __shared__ __align__(16) unsigned short lds[2][32768];  // per buf: A 32KB | B 32KB
  const int t = threadIdx.x;
  const int lane = t & 63;
  const int wid = t >> 6;
  const int wm = wid >> 2, wn = wid & 3;
  const int lr = lane & 15, lg = lane >> 4;
  const int m0 = blockIdx.y * 256, n0 = blockIdx.x * 256;

  f32x4 acc[8][4];
#pragma unroll
  for (int i = 0; i < 8; ++i)
#pragma unroll
    for (int j = 0; j < 4; ++j) acc[i][j] = (f32x4){0.f, 0.f, 0.f, 0.f};

  const int srow = t >> 3;  // 0..63 within a 64-row stage chunk
  const int schk = t & 7;

  auto stage_all = [&](int buf, int kt) {
    const int k0 = kt * 64;
#pragma unroll
    for (int hh = 0; hh < 4; ++hh) {  // A rows 0-127,128-255 then B rows 0-127,128-255
      const unsigned short* src = (hh < 2) ? A : B;
      const int r0 = ((hh < 2) ? m0 : n0) + (hh & 1) * 128;
      char* dst = (char*)lds[buf] + (hh >= 2 ? 32768 : 0) + (hh & 1) * 16384;
#pragma unroll
      for (int i = 0; i < 2; ++i) {
        int row = i * 64 + srow;
        int gc = schk ^ (row & 7);
        gload_lds16(src + (size_t)(r0 + row) * K + k0 + gc * 8, dst + i * 8192 + t * 16);
      }
    }
  };

  stage_all(0, 0);
  __syncthreads();

  const int NT = K >> 6;
#pragma unroll 1
  for (int kt = 0; kt < NT; ++kt) {
    const int cur = kt & 1;
    const char* Ab = (const char*)lds[cur];
    const char* Bb = (const char*)lds[cur] + 32768;
#pragma unroll
    for (int p = 0; p < 4; ++p) {
      if (p == 0 && kt + 1 < NT) stage_all(cur ^ 1, kt + 1);  // async DMA covers this tile's compute
      const int mh = p >> 1, nh = p & 1;
#pragma unroll
      for (int kk = 0; kk < 2; ++kk) {
        bf16x8 af[4], bfr[2];
#pragma unroll
        for (int fm = 0; fm < 4; ++fm) {
          int row = wm * 128 + mh * 64 + fm * 16 + lr;
          af[fm] = *(const bf16x8*)(Ab + row * 128 + (((kk * 4 + lg) ^ (row & 7)) * 16));
        }
#pragma unroll
        for (int fn = 0; fn < 2; ++fn) {
          int row = wn * 64 + nh * 32 + fn * 16 + lr;
          bfr[fn] = *(const bf16x8*)(Bb + row * 128 + (((kk * 4 + lg) ^ (row & 7)) * 16));
        }
        __builtin_amdgcn_s_setprio(1);
#pragma unroll
        for (int fm = 0; fm < 4; ++fm)
#pragma unroll
          for (int fn = 0; fn < 2; ++fn)
            acc[mh * 4 + fm][nh * 2 + fn] =
                __builtin_amdgcn_mfma_f32_16x16x32_bf16(af[fm], bfr[fn], acc[mh * 4 + fm][nh * 2 + fn], 0, 0, 0);
        __builtin_amdgcn_s_setprio(0);
      }
    }
    __syncthreads();  // per-wave vmcnt drain + cross-wave completion of next-tile DMA
  }

#pragma unroll
  for (int fm = 0; fm < 8; ++fm) {
#pragma unroll
    for (int r = 0; r < 4; ++r) {
      int row = m0 + wm * 128 + fm * 16 + lg * 4 + r;
#pragma unroll
      for (int fn = 0; fn < 4; ++fn) {
        int col = n0 + wn * 64 + fn * 16 + lr;
        float v = acc[fm][fn][r];
        if (MODE == 0)
          ((unsigned short*)Cout)[(size_t)row * N + col] = f2bf(v);
        else
          ((float*)Cout)[(size_t)row * N + col] = v + bias[col];
      }
    }
  }
}

// ---------------- causal flash attention v4 (r7-measured; strides updated) ----------------
// qk: [B*T][2048] bf16 (Q cols 0-1023 pre-scaled by 0.125*log2e, K cols 1024-2047)
// vtb: V^T [h*64+d][8192] (col = b*2048 + t); out: [B*T][1024] bf16
__global__ __launch_bounds__(256) void attn_kernel(const unsigned short* __restrict__ qkv,
                                                   const unsigned short* __restrict__ vtb,
                                                   unsigned short* __restrict__ out) {
  __shared__ __align__(16) char kl[2][8192];
  __shared__ __align__(16) char vt[2][8192];
  __shared__ __align__(16) char pl[8192];
  const int t = threadIdx.x;
  const int wid = t >> 6, lane = t & 63;
  const int lr = lane & 15, lg = lane >> 4;
  const int i = blockIdx.x;
  const int xcd = i & 7, s = i >> 3;
  const int bh = xcd + 8 * (s >> 5);
  const int qtile = 31 - (s & 31);
  const int b = bh >> 4, h = bh & 15;
  const size_t baseRow = (size_t)b * 2048;
  const int nkt = qtile + 1;
  const int q0w = qtile * 64 + wid * 16;
  char* pb = pl + wid * 2048;
  const int swP = ((lr & 1) << 4) | ((lr & 12) << 3);
  const int srow = lane >> 3;
  const int sc = lane & 7;

  const unsigned short* qp = qkv + (baseRow + q0w + lr) * 2048 + h * 64 + lg * 8;
  bf16x8 qf0 = *(const bf16x8*)qp;
  bf16x8 qf1 = *(const bf16x8*)(qp + 32);

  f32x4 acc_o[4];
#pragma unroll
  for (int d = 0; d < 4; ++d) acc_o[d] = (f32x4){0.f, 0.f, 0.f, 0.f};
  float l_acc = 0.f;

  const unsigned short* vrow = vtb + (size_t)(h * 64) * 8192 + baseRow;

  auto stage = [&](int kt, int buf) {
#pragma unroll
    for (int ch = 0; ch < 2; ++ch) {
      int kr = ch * 32 + wid * 8 + srow;
      int gc = sc ^ (kr & 7);
      gload_lds16(qkv + (baseRow + kt * 64 + kr) * 2048 + 1024 + h * 64 + gc * 8,
                  &kl[buf][(ch * 256 + t) * 16]);
    }
#pragma unroll
    for (int ch = 0; ch < 2; ++ch) {
      int d = ch * 32 + wid * 8 + srow;
      int gc = sc ^ (((d & 7) ^ (d >> 3)) & 7);
      gload_lds16(vrow + (size_t)d * 8192 + kt * 64 + gc * 8,
                  &vt[buf][(ch * 256 + t) * 16]);
    }
  };

  stage(0, 0);
  __syncthreads();

#pragma unroll 1
  for (int kt = 0; kt < nkt; ++kt) {
    const int cur = kt & 1;
    if (kt + 1 < nkt) stage(kt + 1, cur ^ 1);

    const char* klc = kl[cur];
    f32x4 z[4];
#pragma unroll
    for (int nt = 0; nt < 4; ++nt) {
      int key = nt * 16 + lr;
      const char* kb = klc + key * 128;
      int sw = (key & 7) << 4;
      bf16x8 kf0 = *(const bf16x8*)(kb + ((lg * 16) ^ sw));
      bf16x8 kf1 = *(const bf16x8*)(kb + ((64 + lg * 16) ^ sw));
      f32x4 zz = (f32x4){0.f, 0.f, 0.f, 0.f};
      zz = __builtin_amdgcn_mfma_f32_16x16x32_bf16(kf0, qf0, zz, 0, 0, 0);
      zz = __builtin_amdgcn_mfma_f32_16x16x32_bf16(kf1, qf1, zz, 0, 0, 0);
      z[nt] = zz;
    }
    const bool diag = (kt == qtile);
    const int qg = q0w + lr;
#pragma unroll
    for (int nt = 0; nt < 4; ++nt) {
      union { uint2 v; unsigned short us[4]; } pk;
#pragma unroll
      for (int r = 0; r < 4; ++r) {
        float pv = exp2f(z[nt][r]);
        if (diag) {
          int keyg = kt * 64 + nt * 16 + lg * 4 + r;
          pv = (keyg > qg) ? 0.f : pv;
        }
        l_acc += pv;
        pk.us[r] = f2bf(pv);
      }
      *(uint2*)(pb + lr * 128 + (((nt * 16 + lg * 4) * 2) ^ swP)) = pk.v;
    }
#pragma unroll
    for (int kk = 0; kk < 2; ++kk) {
      bf16x8 pfr = *(const bf16x8*)(pb + lr * 128 + ((kk * 64 + lg * 16) ^ swP));
#pragma unroll
      for (int dt = 0; dt < 4; ++dt) {
        int d = dt * 16 + lr;
        int swv = (((d & 7) ^ ((d >> 3) & 7)) << 4);
        bf16x8 vf = *(const bf16x8*)(vt[cur] + d * 128 + ((kk * 64 + lg * 16) ^ swv));
        acc_o[dt] = __builtin_amdgcn_mfma_f32_16x16x32_bf16(pfr, vf, acc_o[dt], 0, 0, 0);
      }
    }
    __syncthreads();
  }

  float lsum = l_acc;
  lsum += __shfl_xor(lsum, 16);
  lsum += __shfl_xor(lsum, 32);
#pragma unroll
  for (int r = 0; r < 4; ++r) {
    float inv = 1.0f / __shfl(lsum, lg * 4 + r);
    unsigned short* op = out + (baseRow + q0w + lg * 4 + r) * 1024 + h * 64;
#pragma unroll
    for (int dt = 0; dt < 4; ++dt) op[dt * 16 + lr] = f2bf(acc_o[dt][r] * inv);
  }
}

extern "C" void kernel_launch(void* const* d_in, const int* in_sizes, int n_in,
                              void* d_out, int out_size, void* d_ws, size_t ws_size,
                              hipStream_t stream) {
  const float* x = (const float*)d_in[0];
  const float* Wq = (const float*)d_in[1];
  const float* Wk = (const float*)d_in[2];
  const float* Wv = (const float*)d_in[3];
  const float* Aq = (const float*)d_in[4];
  const float* Bq = (const float*)d_in[5];
  const float* Ak = (const float*)d_in[6];
  const float* Bk = (const float*)d_in[7];
  const float* Av = (const float*)d_in[8];
  const float* Bv = (const float*)d_in[9];
  const float* Wp = (const float*)d_in[10];
  const float* bp = (const float*)d_in[11];
  const float* Ap = (const float*)d_in[12];
  const float* Bp = (const float*)d_in[13];

  // carve (bf16 elems): xb 16.8MB (reused as attn out) | weffQK 4MB | weffV 2MB |
  //                     wpeff 2MB | qkb 33.5MB | vtb 16.8MB  => peak ~75.5MB
  unsigned short* xb = (unsigned short*)d_ws;
  unsigned short* weff = xb + 8388608;       // [2048][1024]: Q rows 0-1023, K rows 1024-2047
  unsigned short* weffV = weff + 2097152;    // [1024][1024]
  unsigned short* wpeff = weffV + 1048576;   // [1024][1024]
  unsigned short* qkb = wpeff + 1048576;     // [8192][2048]
  unsigned short* vtb = qkb + 16777216;      // [1024][8192]
  unsigned short* attb = xb;                 // alias: x dead after QK + VT GEMMs

  cast_x_kernel<<<4096, 256, 0, stream>>>(x, xb);
  dim3 fg(16, 16);
  fold_head_kernel<<<fg, 256, 0, stream>>>(Wq, Aq, Bq, weff, 0.125f * LOG2E);
  fold_head_kernel<<<fg, 256, 0, stream>>>(Wk, Ak, Bk, weff + 1048576, 1.0f);
  fold_head_kernel<<<fg, 256, 0, stream>>>(Wv, Av, Bv, weffV, 1.0f);
  fold_proj_kernel<<<fg, 256, 0, stream>>>(Wp, Ap, Bp, wpeff);

  // QK GEMM: [8192][1024] x [2048][1024]^T -> qkb
  gemm256_kernel<0><<<dim3(8, 32), 512, 0, stream>>>(xb, weff, (void*)qkb, nullptr, 8192, 2048, 1024);
  // V^T GEMM: [1024][1024] x [8192][1024]^T -> vtb (V transposed for free)
  gemm256_kernel<0><<<dim3(32, 4), 512, 0, stream>>>(weffV, xb, (void*)vtb, nullptr, 1024, 8192, 1024);
  attn_kernel<<<2048, 256, 0, stream>>>(qkb, vtb, attb);
  // proj GEMM: [8192][1024] x [1024][1024]^T + bias -> d_out (fp32)
  gemm256_kernel<1><<<dim3(4, 32), 512, 0, stream>>>(attb, wpeff, d_out, bp, 8192, 1024, 1024);
}

// Round 12
// 304.131 us; speedup vs baseline: 2.3433x; 1.0830x over previous
//
#include <hip/hip_runtime.h>
#include <hip/hip_bf16.h>
#include <stdint.h>

typedef __attribute__((ext_vector_type(4))) float f32x4;
typedef __attribute__((ext_vector_type(8))) short bf16x8;

#define LOG2E 1.44269504088896340736f

__device__ __forceinline__ unsigned short f2bf(float f) {
  union { float f; unsigned u; } c; c.f = f;
  unsigned u = c.u + 0x7FFFu + ((c.u >> 16) & 1u);
  return (unsigned short)(u >> 16);
}

__device__ __forceinline__ void gload_lds16(const void* g, void* l) {
  __builtin_amdgcn_global_load_lds((const __attribute__((address_space(1))) void*)g,
                                   (__attribute__((address_space(3))) void*)l, 16, 0, 0);
}

// ---------------- cast x fp32 -> bf16 ----------------
__global__ __launch_bounds__(256) void cast_x_kernel(const float* __restrict__ x,
                                                     unsigned short* __restrict__ o) {
  int i = blockIdx.x * 256 + threadIdx.x;
  const float4* xv = (const float4*)x;
  float4 a = xv[2 * i], b = xv[2 * i + 1];
  union { uint4 v; unsigned short s[8]; } u;
  u.s[0] = f2bf(a.x); u.s[1] = f2bf(a.y); u.s[2] = f2bf(a.z); u.s[3] = f2bf(a.w);
  u.s[4] = f2bf(b.x); u.s[5] = f2bf(b.y); u.s[6] = f2bf(b.z); u.s[7] = f2bf(b.w);
  ((uint4*)o)[i] = u.v;
}

// ---------------- fold LoRA into per-head weights -> W_eff^T [n][c] bf16 ----------------
__global__ __launch_bounds__(256) void fold_head_kernel(const float* __restrict__ W,
                                                        const float* __restrict__ A,
                                                        const float* __restrict__ Bm,
                                                        unsigned short* __restrict__ outT,
                                                        float scale) {
  int h = blockIdx.x, cb = blockIdx.y;
  __shared__ float Bs[8][64];
  __shared__ unsigned short tile[64][65];
  int t = threadIdx.x;
  if (t < 128) ((float4*)&Bs[0][0])[t] = ((const float4*)(Bm + (size_t)h * 512))[t];
  __syncthreads();
  int cl = t >> 2;
  int c = cb * 64 + cl;
  int dbase = (t & 3) * 16;
  float4 a0 = *(const float4*)(A + (size_t)h * 8192 + c * 8);
  float4 a1 = *(const float4*)(A + (size_t)h * 8192 + c * 8 + 4);
  const float* Wc = W + (size_t)h * 65536 + (size_t)c * 64;
#pragma unroll
  for (int j = 0; j < 16; ++j) {
    int d = dbase + j;
    float acc = a0.x * Bs[0][d] + a0.y * Bs[1][d] + a0.z * Bs[2][d] + a0.w * Bs[3][d] +
                a1.x * Bs[4][d] + a1.y * Bs[5][d] + a1.z * Bs[6][d] + a1.w * Bs[7][d];
    tile[cl][d] = f2bf(scale * (Wc[d] + 2.0f * acc));
  }
  __syncthreads();
#pragma unroll
  for (int i = 0; i < 16; ++i) {
    int idx = i * 256 + t;
    int d = idx >> 6, c2 = idx & 63;
    outT[(size_t)(h * 64 + d) * 1024 + cb * 64 + c2] = tile[c2][d];
  }
}

// ---------------- fold proj LoRA -> Wp_eff^T [n][c] bf16 ----------------
__global__ __launch_bounds__(256) void fold_proj_kernel(const float* __restrict__ W,
                                                        const float* __restrict__ A,
                                                        const float* __restrict__ Bm,
                                                        unsigned short* __restrict__ outT) {
  int nb = blockIdx.x, cb = blockIdx.y;
  __shared__ float Bs[8][64];
  __shared__ unsigned short tile[64][65];
  int t = threadIdx.x;
  if (t < 128) {
    int r = t >> 4, dc = t & 15;
    *(float4*)&Bs[r][dc * 4] = *(const float4*)(Bm + (size_t)r * 1024 + nb * 64 + dc * 4);
  }
  __syncthreads();
  int cl = t >> 2;
  int c = cb * 64 + cl;
  int dbase = (t & 3) * 16;
  float4 a0 = *(const float4*)(A + (size_t)c * 8);
  float4 a1 = *(const float4*)(A + (size_t)c * 8 + 4);
  const float* Wc = W + (size_t)c * 1024 + nb * 64;
#pragma unroll
  for (int j = 0; j < 16; ++j) {
    int d = dbase + j;
    float acc = a0.x * Bs[0][d] + a0.y * Bs[1][d] + a0.z * Bs[2][d] + a0.w * Bs[3][d] +
                a1.x * Bs[4][d] + a1.y * Bs[5][d] + a1.z * Bs[6][d] + a1.w * Bs[7][d];
    tile[cl][d] = f2bf(Wc[d] + 2.0f * acc);
  }
  __syncthreads();
#pragma unroll
  for (int i = 0; i < 16; ++i) {
    int idx = i * 256 + t;
    int d = idx >> 6, c2 = idx & 63;
    outT[(size_t)(nb * 64 + d) * 1024 + cb * 64 + c2] = tile[c2][d];
  }
}

// ---------------- 256xBN GEMM: C[M][N] = A[M][K]*B[N][K]^T, bf16 in, fp32 acc ----------------
// 512 thr = 8 waves (2M x 4N); BK=64 double-buffered; global_load_lds staging with
// pre-swizzled source (chunk c' = c ^ (row&7)); 4 quadrant-phases/K-tile, setprio MFMA.
// BN in {128, 256}. MODE 0: bf16 out; MODE 1: fp32 out + bias.
template <int BN, int MODE>
__global__ __launch_bounds__(512) void gemm256_kernel(const unsigned short* __restrict__ A,
                                                      const unsigned short* __restrict__ B,
                                                      void* __restrict__ Cout,
                                                      const float* __restrict__ bias,
                                                      int M, int N, int K) {
  constexpr int WN = BN / 4;    // wave n-tile
  constexpr int HN = BN / 8;    // phase n-half
  constexpr int FN = BN / 128;  // n-frags per phase
  __shared__ __align__(16) char lds[2][(256 + BN) * 128];  // A 32KB | B BN*128B
  const int t = threadIdx.x;
  const int lane = t & 63;
  const int wid = t >> 6;
  const int wm = wid >> 2, wn = wid & 3;
  const int lr = lane & 15, lg = lane >> 4;
  const int m0 = blockIdx.y * 256, n0 = blockIdx.x * BN;

  f32x4 acc[8][2 * FN];
#pragma unroll
  for (int i = 0; i < 8; ++i)
#pragma unroll
    for (int j = 0; j < 2 * FN; ++j) acc[i][j] = (f32x4){0.f, 0.f, 0.f, 0.f};

  const int srow = t >> 3;  // 0..63
  const int schk = t & 7;

  auto stage_all = [&](int buf, int kt) {
    const int k0 = kt * 64;
#pragma unroll
    for (int g = 0; g < 2; ++g)  // A: two 128-row groups
#pragma unroll
      for (int i2 = 0; i2 < 2; ++i2) {
        int row = i2 * 64 + srow;
        int gc = schk ^ (row & 7);
        gload_lds16(A + (size_t)(m0 + g * 128 + row) * K + k0 + gc * 8,
                    lds[buf] + g * 16384 + i2 * 8192 + t * 16);
      }
#pragma unroll
    for (int g = 0; g < BN / 128; ++g)  // B groups
#pragma unroll
      for (int i2 = 0; i2 < 2; ++i2) {
        int row = i2 * 64 + srow;
        int gc = schk ^ (row & 7);
        gload_lds16(B + (size_t)(n0 + g * 128 + row) * K + k0 + gc * 8,
                    lds[buf] + 32768 + g * 16384 + i2 * 8192 + t * 16);
      }
  };

  stage_all(0, 0);
  __syncthreads();

  const int NT = K >> 6;
#pragma unroll 1
  for (int kt = 0; kt < NT; ++kt) {
    const int cur = kt & 1;
    const char* Ab = (const char*)lds[cur];
    const char* Bb = (const char*)lds[cur] + 32768;
#pragma unroll
    for (int p = 0; p < 4; ++p) {
      if (p == 0 && kt + 1 < NT) stage_all(cur ^ 1, kt + 1);  // async DMA covers compute
      const int mh = p >> 1, nh = p & 1;
#pragma unroll
      for (int kk = 0; kk < 2; ++kk) {
        bf16x8 af[4], bfr[FN];
#pragma unroll
        for (int fm = 0; fm < 4; ++fm) {
          int row = wm * 128 + mh * 64 + fm * 16 + lr;
          af[fm] = *(const bf16x8*)(Ab + row * 128 + (((kk * 4 + lg) ^ (row & 7)) * 16));
        }
#pragma unroll
        for (int fn = 0; fn < FN; ++fn) {
          int row = wn * WN + nh * HN + fn * 16 + lr;
          bfr[fn] = *(const bf16x8*)(Bb + row * 128 + (((kk * 4 + lg) ^ (row & 7)) * 16));
        }
        __builtin_amdgcn_s_setprio(1);
#pragma unroll
        for (int fm = 0; fm < 4; ++fm)
#pragma unroll
          for (int fn = 0; fn < FN; ++fn)
            acc[mh * 4 + fm][nh * FN + fn] =
                __builtin_amdgcn_mfma_f32_16x16x32_bf16(af[fm], bfr[fn], acc[mh * 4 + fm][nh * FN + fn], 0, 0, 0);
        __builtin_amdgcn_s_setprio(0);
      }
    }
    __syncthreads();
  }

#pragma unroll
  for (int fm = 0; fm < 8; ++fm) {
#pragma unroll
    for (int r = 0; r < 4; ++r) {
      int row = m0 + wm * 128 + fm * 16 + lg * 4 + r;
#pragma unroll
      for (int fn = 0; fn < 2 * FN; ++fn) {
        int col = n0 + wn * WN + fn * 16 + lr;
        float v = acc[fm][fn][r];
        if (MODE == 0)
          ((unsigned short*)Cout)[(size_t)row * N + col] = f2bf(v);
        else
          ((float*)Cout)[(size_t)row * N + col] = v + bias[col];
      }
    }
  }
}

// ---------------- causal flash attention v5 ----------------
// qk: [B*T][2048] bf16 (Q cols 0-1023 pre-scaled by 0.125*log2e, K cols 1024-2047)
// vtb: V^T [h*64+d][8192] (col = b*2048 + t); out: [B*T][1024] bf16
// v5: cvt_pk bf16 pack (asm), denominator via MFMA(P, ones), setprio MFMA clusters.
__global__ __launch_bounds__(256) void attn_kernel(const unsigned short* __restrict__ qkv,
                                                   const unsigned short* __restrict__ vtb,
                                                   unsigned short* __restrict__ out) {
  __shared__ __align__(16) char kl[2][8192];
  __shared__ __align__(16) char vt[2][8192];
  __shared__ __align__(16) char pl[8192];
  const int t = threadIdx.x;
  const int wid = t >> 6, lane = t & 63;
  const int lr = lane & 15, lg = lane >> 4;
  const int i = blockIdx.x;
  const int xcd = i & 7, s = i >> 3;
  const int bh = xcd + 8 * (s >> 5);
  const int qtile = 31 - (s & 31);
  const int b = bh >> 4, h = bh & 15;
  const size_t baseRow = (size_t)b * 2048;
  const int nkt = qtile + 1;
  const int q0w = qtile * 64 + wid * 16;
  char* pb = pl + wid * 2048;
  const int swP = ((lr & 1) << 4) | ((lr & 12) << 3);
  const int srow = lane >> 3;
  const int sc = lane & 7;

  const unsigned short* qp = qkv + (baseRow + q0w + lr) * 2048 + h * 64 + lg * 8;
  bf16x8 qf0 = *(const bf16x8*)qp;
  bf16x8 qf1 = *(const bf16x8*)(qp + 32);

  const bf16x8 onesf = {(short)0x3F80, (short)0x3F80, (short)0x3F80, (short)0x3F80,
                        (short)0x3F80, (short)0x3F80, (short)0x3F80, (short)0x3F80};

  f32x4 acc_o[4];
#pragma unroll
  for (int d = 0; d < 4; ++d) acc_o[d] = (f32x4){0.f, 0.f, 0.f, 0.f};
  f32x4 acc_l = (f32x4){0.f, 0.f, 0.f, 0.f};  // l[q=lg*4+r] via MFMA(P, ones)

  const unsigned short* vrow = vtb + (size_t)(h * 64) * 8192 + baseRow;

  auto stage = [&](int kt, int buf) {
#pragma unroll
    for (int ch = 0; ch < 2; ++ch) {
      int kr = ch * 32 + wid * 8 + srow;
      int gc = sc ^ (kr & 7);
      gload_lds16(qkv + (baseRow + kt * 64 + kr) * 2048 + 1024 + h * 64 + gc * 8,
                  &kl[buf][(ch * 256 + t) * 16]);
    }
#pragma unroll
    for (int ch = 0; ch < 2; ++ch) {
      int d = ch * 32 + wid * 8 + srow;
      int gc = sc ^ (((d & 7) ^ (d >> 3)) & 7);
      gload_lds16(vrow + (size_t)d * 8192 + kt * 64 + gc * 8,
                  &vt[buf][(ch * 256 + t) * 16]);
    }
  };

  stage(0, 0);
  __syncthreads();

#pragma unroll 1
  for (int kt = 0; kt < nkt; ++kt) {
    const int cur = kt & 1;
    if (kt + 1 < nkt) stage(kt + 1, cur ^ 1);

    const char* klc = kl[cur];
    f32x4 z[4];
#pragma unroll
    for (int nt = 0; nt < 4; ++nt) {
      int key = nt * 16 + lr;
      const char* kb = klc + key * 128;
      int sw = (key & 7) << 4;
      bf16x8 kf0 = *(const bf16x8*)(kb + ((lg * 16) ^ sw));
      bf16x8 kf1 = *(const bf16x8*)(kb + ((64 + lg * 16) ^ sw));
      f32x4 zz = (f32x4){0.f, 0.f, 0.f, 0.f};
      __builtin_amdgcn_s_setprio(1);
      zz = __builtin_amdgcn_mfma_f32_16x16x32_bf16(kf0, qf0, zz, 0, 0, 0);
      zz = __builtin_amdgcn_mfma_f32_16x16x32_bf16(kf1, qf1, zz, 0, 0, 0);
      __builtin_amdgcn_s_setprio(0);
      z[nt] = zz;
    }
    const bool diag = (kt == qtile);
    const int qg = q0w + lr;
#pragma unroll
    for (int nt = 0; nt < 4; ++nt) {
      float pv[4];
#pragma unroll
      for (int r = 0; r < 4; ++r) {
        float e = exp2f(z[nt][r]);
        if (diag) {
          int keyg = kt * 64 + nt * 16 + lg * 4 + r;
          e = (keyg > qg) ? 0.f : e;
        }
        pv[r] = e;
      }
      unsigned w0, w1;
      asm("v_cvt_pk_bf16_f32 %0, %1, %2" : "=v"(w0) : "v"(pv[0]), "v"(pv[1]));
      asm("v_cvt_pk_bf16_f32 %0, %1, %2" : "=v"(w1) : "v"(pv[2]), "v"(pv[3]));
      uint2 pk2;
      pk2.x = w0;
      pk2.y = w1;
      *(uint2*)(pb + lr * 128 + (((nt * 16 + lg * 4) * 2) ^ swP)) = pk2;
    }
#pragma unroll
    for (int kk = 0; kk < 2; ++kk) {
      bf16x8 pfr = *(const bf16x8*)(pb + lr * 128 + ((kk * 64 + lg * 16) ^ swP));
      __builtin_amdgcn_s_setprio(1);
#pragma unroll
      for (int dt = 0; dt < 4; ++dt) {
        int d = dt * 16 + lr;
        int swv = (((d & 7) ^ ((d >> 3) & 7)) << 4);
        bf16x8 vf = *(const bf16x8*)(vt[cur] + d * 128 + ((kk * 64 + lg * 16) ^ swv));
        acc_o[dt] = __builtin_amdgcn_mfma_f32_16x16x32_bf16(pfr, vf, acc_o[dt], 0, 0, 0);
      }
      acc_l = __builtin_amdgcn_mfma_f32_16x16x32_bf16(pfr, onesf, acc_l, 0, 0, 0);
      __builtin_amdgcn_s_setprio(0);
    }
    __syncthreads();
  }

  // epilogue: acc_l[r] = l[q = lg*4+r] (uniform across lr) -> direct normalize
#pragma unroll
  for (int r = 0; r < 4; ++r) {
    float inv = 1.0f / acc_l[r];
    unsigned short* op = out + (baseRow + q0w + lg * 4 + r) * 1024 + h * 64;
#pragma unroll
    for (int dt = 0; dt < 4; ++dt) op[dt * 16 + lr] = f2bf(acc_o[dt][r] * inv);
  }
}

extern "C" void kernel_launch(void* const* d_in, const int* in_sizes, int n_in,
                              void* d_out, int out_size, void* d_ws, size_t ws_size,
                              hipStream_t stream) {
  const float* x = (const float*)d_in[0];
  const float* Wq = (const float*)d_in[1];
  const float* Wk = (const float*)d_in[2];
  const float* Wv = (const float*)d_in[3];
  const float* Aq = (const float*)d_in[4];
  const float* Bq = (const float*)d_in[5];
  const float* Ak = (const float*)d_in[6];
  const float* Bk = (const float*)d_in[7];
  const float* Av = (const float*)d_in[8];
  const float* Bv = (const float*)d_in[9];
  const float* Wp = (const float*)d_in[10];
  const float* bp = (const float*)d_in[11];
  const float* Ap = (const float*)d_in[12];
  const float* Bp = (const float*)d_in[13];

  // carve (bf16 elems): xb 16.8MB (reused as attn out) | weffQK 4MB | weffV 2MB |
  //                     wpeff 2MB | qkb 33.5MB | vtb 16.8MB  => peak ~75.5MB
  unsigned short* xb = (unsigned short*)d_ws;
  unsigned short* weff = xb + 8388608;       // [2048][1024]: Q rows 0-1023, K rows 1024-2047
  unsigned short* weffV = weff + 2097152;    // [1024][1024]
  unsigned short* wpeff = weffV + 1048576;   // [1024][1024]
  unsigned short* qkb = wpeff + 1048576;     // [8192][2048]
  unsigned short* vtb = qkb + 16777216;      // [1024][8192]
  unsigned short* attb = xb;                 // alias: x dead after QK + VT GEMMs

  cast_x_kernel<<<4096, 256, 0, stream>>>(x, xb);
  dim3 fg(16, 16);
  fold_head_kernel<<<fg, 256, 0, stream>>>(Wq, Aq, Bq, weff, 0.125f * LOG2E);
  fold_head_kernel<<<fg, 256, 0, stream>>>(Wk, Ak, Bk, weff + 1048576, 1.0f);
  fold_head_kernel<<<fg, 256, 0, stream>>>(Wv, Av, Bv, weffV, 1.0f);
  fold_proj_kernel<<<fg, 256, 0, stream>>>(Wp, Ap, Bp, wpeff);

  // QK GEMM: [8192][1024] x [2048][1024]^T -> qkb   (grid 256 = full machine)
  gemm256_kernel<256, 0><<<dim3(8, 32), 512, 0, stream>>>(xb, weff, (void*)qkb, nullptr, 8192, 2048, 1024);
  // V^T GEMM: [1024][1024] x [8192][1024]^T -> vtb  (grid 64x4 = 256)
  gemm256_kernel<128, 0><<<dim3(64, 4), 512, 0, stream>>>(weffV, xb, (void*)vtb, nullptr, 1024, 8192, 1024);
  attn_kernel<<<2048, 256, 0, stream>>>(qkb, vtb, attb);
  // proj GEMM: [8192][1024] x [1024][1024]^T + bias -> d_out (grid 8x32 = 256)
  gemm256_kernel<128, 1><<<dim3(8, 32), 512, 0, stream>>>(attb, wpeff, d_out, bp, 8192, 1024, 1024);
}